// Round 6
// baseline (622.488 us; speedup 1.0000x reference)
//
#include <hip/hip_runtime.h>
#include <hip/hip_cooperative_groups.h>

namespace cg = cooperative_groups;

// DSR loss: R_t = dot16(w_t,x_t); A_t = c*A_{t-1}+eta*R_t (c=0.99), B_t
// likewise with R^2; D_t from (A_prev,B_prev); out = -mean(D).
//
// R6: ONE cooperative kernel. Phase A: dots -> LDS (no global R), intra-block
// scan, publish per-chunk affine aggregate. grid.sync. Phase B: every block
// redundantly composes its exclusive prefix from the aggregate array (64
// lanes x ~16 serial combines + wave combine; aggs array is 23 KB, L2
// broadcast). Phase C: replay D from LDS, fp64 atomicAdd. grid.sync.
// Block 0 writes the scalar. No lookback serialization (R4's mistake), no
// extra passes over R (R5's k2). fp64 internal math (absmax 0.0 in R1-R5).

#define D_ETA 0.01
#define D_C   (1.0 - D_ETA)
#define D_EPS 1e-8

constexpr int BLOCK = 256;
constexpr int CHUNK = 2048;          // rows per chunk
constexpr int LPT   = CHUNK / BLOCK; // 8 rows per thread
constexpr int GRP   = CHUNK / 64;    // 32 row-groups of 64
constexpr int MAXNB = 1024;          // co-residency cap (safe: ~15.4KB LDS, <=8 blk/CU)

#define SCOPE __HIP_MEMORY_SCOPE_AGENT

__device__ __forceinline__ int pidx(int i) { return i + (i >> 3); }
constexpr int RS_SIZE = CHUNK + CHUNK / 8;

__device__ __forceinline__ double dot4d(float4 a, float4 b) {
    return (double)a.x * (double)b.x + (double)a.y * (double)b.y
         + (double)a.z * (double)b.z + (double)a.w * (double)b.w;
}

__device__ __forceinline__ float row_R(const float* __restrict__ w,
                                       const float* __restrict__ x,
                                       long long row) {
    const float4* w4 = (const float4*)(w + row * 16);
    const float4* x4 = (const float4*)(x + row * 16);
    double r = 0.0;
#pragma unroll
    for (int q = 0; q < 4; ++q) r += dot4d(w4[q], x4[q]);
    return (float)r;
}

// ordered wave-64 composition; lane 0 ends with T_{63}∘..∘T_0 (lane order =
// application order). Verified (R5 passed, absmax 0.0).
__device__ __forceinline__ void wave_combine(double& m, double& a, double& b) {
    int lane = threadIdx.x & 63;
#pragma unroll
    for (int off = 1; off < 64; off <<= 1) {
        double pm = __shfl_down(m, off, 64);
        double pa = __shfl_down(a, off, 64);
        double pb = __shfl_down(b, off, 64);
        if (lane + off < 64) {          // partner applied AFTER self
            a = pm * a + pa;
            b = pm * b + pb;
            m = pm * m;
        }
    }
}

// Hillis-Steele inclusive scan over 256 affine transforms.
__device__ __forceinline__ void block_scan(double& m, double& sA, double& sB,
                                           double* mS, double* aS, double* bS) {
    int tid = threadIdx.x;
    mS[tid] = m; aS[tid] = sA; bS[tid] = sB;
    __syncthreads();
#pragma unroll
    for (int off = 1; off < BLOCK; off <<= 1) {
        double pm = 1.0, pa = 0.0, pb = 0.0;
        if (tid >= off) { pm = mS[tid - off]; pa = aS[tid - off]; pb = bS[tid - off]; }
        __syncthreads();
        if (tid >= off) {
            sA = m * pa + sA;
            sB = m * pb + sB;
            m  = pm * m;
        }
        mS[tid] = m; aS[tid] = sA; bS[tid] = sB;
        __syncthreads();
    }
}

// ---------------- cooperative mega-kernel ----------------
__global__ __launch_bounds__(BLOCK) void k_coop(
    const float* __restrict__ w, const float* __restrict__ x,
    int nrows, int nb,
    double* __restrict__ aggs,   // [nb*3]
    double* __restrict__ acc,    // [1]
    float*  __restrict__ out)
{
    __shared__ float  Rs[RS_SIZE];
    __shared__ double mS[BLOCK], aS[BLOCK], bS[BLOCK];
    __shared__ double exAB[2];
    __shared__ double wsum[BLOCK / 64];

    int tid = threadIdx.x;
    int cid = blockIdx.x;
    long long base = (long long)cid * CHUNK;

    if (cid == 0 && tid == 0) *acc = 0.0;

    // ---- phase A1: dots -> LDS ----
    int q    = tid & 3;
    int rsub = tid >> 2;
    const float4* w4 = (const float4*)w;
    const float4* x4 = (const float4*)x;
    long long f0 = base * 4 + tid;

    if (base + CHUNK <= (long long)nrows) {
#pragma unroll
        for (int g = 0; g < GRP; g += 4) {
            float4 a0 = w4[f0 + (long long)(g + 0) * 256];
            float4 a1 = w4[f0 + (long long)(g + 1) * 256];
            float4 a2 = w4[f0 + (long long)(g + 2) * 256];
            float4 a3 = w4[f0 + (long long)(g + 3) * 256];
            float4 b0 = x4[f0 + (long long)(g + 0) * 256];
            float4 b1 = x4[f0 + (long long)(g + 1) * 256];
            float4 b2 = x4[f0 + (long long)(g + 2) * 256];
            float4 b3 = x4[f0 + (long long)(g + 3) * 256];
            double p0 = dot4d(a0, b0), p1 = dot4d(a1, b1);
            double p2 = dot4d(a2, b2), p3 = dot4d(a3, b3);
            p0 += __shfl_xor(p0, 1, 64); p0 += __shfl_xor(p0, 2, 64);
            p1 += __shfl_xor(p1, 1, 64); p1 += __shfl_xor(p1, 2, 64);
            p2 += __shfl_xor(p2, 1, 64); p2 += __shfl_xor(p2, 2, 64);
            p3 += __shfl_xor(p3, 1, 64); p3 += __shfl_xor(p3, 2, 64);
            if (q == 0) {
                Rs[pidx((g + 0) * 64 + rsub)] = (float)p0;
                Rs[pidx((g + 1) * 64 + rsub)] = (float)p1;
                Rs[pidx((g + 2) * 64 + rsub)] = (float)p2;
                Rs[pidx((g + 3) * 64 + rsub)] = (float)p3;
            }
        }
    } else {
        for (int g = 0; g < GRP; ++g) {
            long long row = base + g * 64 + rsub;
            double p = 0.0;
            if (row < nrows) p = dot4d(w4[row * 4 + q], x4[row * 4 + q]);
            p += __shfl_xor(p, 1, 64);
            p += __shfl_xor(p, 2, 64);
            if (q == 0) Rs[pidx(g * 64 + rsub)] = (float)p;
        }
    }
    __syncthreads();

    // ---- phase A2: intra-block scan; thread 255 holds chunk aggregate ----
    int start = tid * LPT;
    long long rem = (long long)nrows - (base + start);
    int len = rem >= LPT ? LPT : (rem > 0 ? (int)rem : 0);
    double m = 1.0, sA = 0.0, sB = 0.0;
    for (int k = 0; k < len; ++k) {
        double r = (double)Rs[pidx(start + k)];
        sA = D_C * sA + D_ETA * r;
        sB = D_C * sB + D_ETA * (r * r);
        m *= D_C;
    }
    block_scan(m, sA, sB, mS, aS, bS);
    if (tid == BLOCK - 1) {
        double* ag = aggs + (size_t)cid * 3;
        ag[0] = m; ag[1] = sA; ag[2] = sB;
    }
    __threadfence();

    cg::this_grid().sync();

    // ---- phase B: redundant exclusive prefix over aggs[0..cid) ----
    if (tid < 64) {
        int K = (cid + 63) >> 6;
        int lo = tid * K;
        int hi = lo + K; if (hi > cid) hi = cid;
        double pm = 1.0, pa = 0.0, pb = 0.0;
        for (int j = lo; j < hi; ++j) {
            const double* ag = aggs + (size_t)j * 3;
            double jm = ag[0], ja = ag[1], jb = ag[2];
            pa = jm * pa + ja;
            pb = jm * pb + jb;
            pm = jm * pm;
        }
        wave_combine(pm, pa, pb);
        if (tid == 0) {
            exAB[0] = pa;                 // A0 = pm*0 + pa
            exAB[1] = pm * D_EPS + pb;    // B0 = pm*eps + pb
        }
    }
    __syncthreads();

    // ---- phase C: replay D from LDS ----
    double em = 1.0, ea = 0.0, eb = 0.0;
    if (tid > 0) { em = mS[tid - 1]; ea = aS[tid - 1]; eb = bS[tid - 1]; }
    double A = em * exAB[0] + ea;
    double B = em * exAB[1] + eb;

    double dsum = 0.0;
    for (int k = 0; k < len; ++k) {
        double r = (double)Rs[pidx(start + k)];
        double dA = D_ETA * (r - A);
        double dB = D_ETA * (r * r - B);
        double var = B - A * A;
        if (var < D_EPS) var = D_EPS;
        double denom = var * sqrt(var);
        dsum += (B * dA - 0.5 * A * dB) / denom;
        A += dA;
        B += dB;
    }
#pragma unroll
    for (int off = 32; off > 0; off >>= 1) dsum += __shfl_down(dsum, off, 64);
    if ((tid & 63) == 0) wsum[tid >> 6] = dsum;
    __syncthreads();
    if (tid == 0) {
        double bs = wsum[0] + wsum[1] + wsum[2] + wsum[3];
        __hip_atomic_fetch_add(acc, bs, __ATOMIC_RELAXED, SCOPE);
    }

    cg::this_grid().sync();

    if (cid == 0 && tid == 0)
        out[0] = (float)(-(*acc) / (double)nrows);
}

// ================= fallback path (nb > MAXNB): R5 structure =================
__global__ __launch_bounds__(64) void k0_init(unsigned* __restrict__ ctl)
{
    if (threadIdx.x < 4) ctl[threadIdx.x] = 0u;
}

__global__ __launch_bounds__(BLOCK) void k1_fb(
    const float* __restrict__ w, const float* __restrict__ x, int nrows,
    float* __restrict__ Rws, double* __restrict__ aggs)
{
    __shared__ float Rs[RS_SIZE];
    __shared__ double wM[4], wA[4], wB[4];
    int tid = threadIdx.x;
    int q = tid & 3, rsub = tid >> 2;
    long long base = (long long)blockIdx.x * CHUNK;
    const float4* w4 = (const float4*)w;
    const float4* x4 = (const float4*)x;
    for (int g = 0; g < GRP; ++g) {
        long long row = base + g * 64 + rsub;
        double p = 0.0;
        if (row < nrows) p = dot4d(w4[row * 4 + q], x4[row * 4 + q]);
        p += __shfl_xor(p, 1, 64);
        p += __shfl_xor(p, 2, 64);
        if (q == 0) {
            Rs[pidx(g * 64 + rsub)] = (float)p;
            if (Rws && row < nrows) Rws[row] = (float)p;
        }
    }
    __syncthreads();
    int start = tid * LPT;
    long long rem = (long long)nrows - (base + start);
    int len = rem >= LPT ? LPT : (rem > 0 ? (int)rem : 0);
    double m = 1.0, sA = 0.0, sB = 0.0;
    for (int k = 0; k < len; ++k) {
        double r = (double)Rs[pidx(start + k)];
        sA = D_C * sA + D_ETA * r;
        sB = D_C * sB + D_ETA * (r * r);
        m *= D_C;
    }
    wave_combine(m, sA, sB);
    int wv = tid >> 6;
    if ((tid & 63) == 0) { wM[wv] = m; wA[wv] = sA; wB[wv] = sB; }
    __syncthreads();
    if (tid == 0) {
        double cm = wM[0], ca = wA[0], cb = wB[0];
#pragma unroll
        for (int v = 1; v < 4; ++v) {
            ca = wM[v] * ca + wA[v];
            cb = wM[v] * cb + wB[v];
            cm = wM[v] * cm;
        }
        double* ag = aggs + (size_t)blockIdx.x * 3;
        ag[0] = cm; ag[1] = ca; ag[2] = cb;
    }
}

__global__ __launch_bounds__(BLOCK) void k2_fb(
    const float* __restrict__ Rws,
    const float* __restrict__ w, const float* __restrict__ x, int nrows,
    const double* __restrict__ aggs, int nb,
    double* __restrict__ acc, unsigned* __restrict__ done,
    float* __restrict__ out)
{
    __shared__ double mS[BLOCK], aS[BLOCK], bS[BLOCK];
    __shared__ double exAB[2];
    __shared__ double wsum[BLOCK / 64];
    int tid = threadIdx.x;
    int cid = blockIdx.x;
    long long g0 = (long long)cid * CHUNK + (long long)tid * LPT;
    long long rem = (long long)nrows - g0;
    int len = rem >= LPT ? LPT : (rem > 0 ? (int)rem : 0);

    float rv[LPT];
    if (Rws) {
        for (int k = 0; k < len; ++k) rv[k] = Rws[g0 + k];
    } else {
        for (int k = 0; k < len; ++k) rv[k] = row_R(w, x, g0 + k);
    }
    double m = 1.0, sA = 0.0, sB = 0.0;
    for (int k = 0; k < len; ++k) {
        double r = (double)rv[k];
        sA = D_C * sA + D_ETA * r;
        sB = D_C * sB + D_ETA * (r * r);
        m *= D_C;
    }
    block_scan(m, sA, sB, mS, aS, bS);
    if (tid < 64) {
        int K = (cid + 63) >> 6;
        int lo = tid * K;
        int hi = lo + K; if (hi > cid) hi = cid;
        double pm = 1.0, pa = 0.0, pb = 0.0;
        for (int j = lo; j < hi; ++j) {
            const double* ag = aggs + (size_t)j * 3;
            double jm = ag[0], ja = ag[1], jb = ag[2];
            pa = jm * pa + ja;
            pb = jm * pb + jb;
            pm = jm * pm;
        }
        wave_combine(pm, pa, pb);
        if (tid == 0) { exAB[0] = pa; exAB[1] = pm * D_EPS + pb; }
    }
    __syncthreads();
    double em = 1.0, ea = 0.0, eb = 0.0;
    if (tid > 0) { em = mS[tid - 1]; ea = aS[tid - 1]; eb = bS[tid - 1]; }
    double A = em * exAB[0] + ea;
    double B = em * exAB[1] + eb;
    double dsum = 0.0;
    for (int k = 0; k < len; ++k) {
        double r = (double)rv[k];
        double dA = D_ETA * (r - A);
        double dB = D_ETA * (r * r - B);
        double var = B - A * A;
        if (var < D_EPS) var = D_EPS;
        double denom = var * sqrt(var);
        dsum += (B * dA - 0.5 * A * dB) / denom;
        A += dA;
        B += dB;
    }
#pragma unroll
    for (int off = 32; off > 0; off >>= 1) dsum += __shfl_down(dsum, off, 64);
    if ((tid & 63) == 0) wsum[tid >> 6] = dsum;
    __syncthreads();
    if (tid == 0) {
        double bs = wsum[0] + wsum[1] + wsum[2] + wsum[3];
        __hip_atomic_fetch_add(acc, bs, __ATOMIC_RELAXED, SCOPE);
        unsigned r = __hip_atomic_fetch_add(done, 1u, __ATOMIC_ACQ_REL, SCOPE);
        if (r == (unsigned)(nb - 1)) {
            double total = __hip_atomic_load(acc, __ATOMIC_RELAXED, SCOPE);
            out[0] = (float)(-total / (double)nrows);
        }
    }
}

extern "C" void kernel_launch(void* const* d_in, const int* in_sizes, int n_in,
                              void* d_out, int out_size, void* d_ws, size_t ws_size,
                              hipStream_t stream)
{
    const float* w = (const float*)d_in[0];
    const float* x = (const float*)d_in[1];
    int nrows = in_sizes[0] / 16;
    int nb = (nrows + CHUNK - 1) / CHUNK;

    // ws: [acc f64 | done u32 | pad to 64] [aggs nb*3 f64] [R floats (fb)]
    unsigned* ctl  = (unsigned*)d_ws;
    double*   acc  = (double*)d_ws;
    unsigned* done = ctl + 2;
    double*   aggs = (double*)((char*)d_ws + 64);
    size_t roff = (64 + (size_t)nb * 3 * sizeof(double) + 255) & ~(size_t)255;
    float* Rws = nullptr;
    if (ws_size >= roff + (size_t)nrows * sizeof(float))
        Rws = (float*)((char*)d_ws + roff);

    if (nb <= MAXNB) {
        float* out = (float*)d_out;
        void* args[] = { (void*)&w, (void*)&x, (void*)&nrows, (void*)&nb,
                         (void*)&aggs, (void*)&acc, (void*)&out };
        hipLaunchCooperativeKernel((const void*)k_coop, dim3(nb), dim3(BLOCK),
                                   args, 0, stream);
    } else {
        k0_init<<<1, 64, 0, stream>>>(ctl);
        k1_fb<<<nb, BLOCK, 0, stream>>>(w, x, nrows, Rws, aggs);
        k2_fb<<<nb, BLOCK, 0, stream>>>(Rws, w, x, nrows, aggs, nb,
                                        acc, done, (float*)d_out);
    }
}

// Round 7
// 287.202 us; speedup vs baseline: 2.1674x; 2.1674x over previous
//
#include <hip/hip_runtime.h>

// DSR loss: R_t = sum_i w[t,i]*x[t,i];  A_t = c*A_{t-1} + eta*R_t (c=0.99),
// B_t likewise with R^2;  D_t from (A_prev,B_prev);  out = -sum(D)/B.
//
// R7 = revert to R2 (best measured: 286 us). Session laws learned R1-R6:
//  - the 256MB streaming kernel is pinned at ~100us regardless of body/
//    occupancy/MLP/data-source (latency/clock floor, not controllable);
//  - cross-block sync (lookback R4, coop grid.sync R6) costs +330us flat;
//  - staggered per-block atomics are free; kernel boundaries are the cheap
//    grid barrier;
//  - wall - kernelsum ~ 170us fixed harness tax (restore/poison).
// K1 = pure streaming dot (unit-stride coalesced, fp64 dot -> fp32 R).
// K2/K3/K4/K5 = parallel linear-recurrence scan + replay over R (8 MB,
// cache-resident). fp64 internal math (absmax 0.0 in all passing rounds).

#define D_ETA 0.01
#define D_C   (1.0 - D_ETA)
#define D_EPS 1e-8

constexpr int BLOCK = 256;
constexpr int K1_ROWS = 256;         // rows per K1 block (4 iters x 64 rows)
constexpr int CHUNK = 2048;          // rows per scan block
constexpr int LPT   = CHUNK / BLOCK; // 8 rows per thread

// fallback (ws too small): fp64 dot for one row
__device__ __forceinline__ float row_R(const float* __restrict__ w,
                                       const float* __restrict__ x,
                                       long long row) {
    const float4* w4 = (const float4*)(w + row * 16);
    const float4* x4 = (const float4*)(x + row * 16);
    double r = 0.0;
#pragma unroll
    for (int q = 0; q < 4; ++q) {
        float4 a = w4[q];
        float4 b = x4[q];
        r += (double)a.x * (double)b.x;
        r += (double)a.y * (double)b.y;
        r += (double)a.z * (double)b.z;
        r += (double)a.w * (double)b.w;
    }
    return (float)r;
}

// ---------------- K1: streaming dot products ----------------
// 4 consecutive lanes own one row; each lane loads one contiguous float4.
// Per wave-instruction: 64 lanes x 16 B contiguous = 1 KB. Quarter-dot in
// fp64, cross-lane reduce over the 4 lanes, lane 0-of-4 stores fp32 R.
__global__ __launch_bounds__(BLOCK) void k1_dots(
    const float* __restrict__ w, const float* __restrict__ x, int nrows,
    float* __restrict__ R)
{
    int tid = threadIdx.x;
    int q    = tid & 3;   // which float4 within the row
    int rsub = tid >> 2;  // row within group of 64
    long long base = (long long)blockIdx.x * K1_ROWS;
    const float4* w4 = (const float4*)w;
    const float4* x4 = (const float4*)x;
#pragma unroll
    for (int it = 0; it < K1_ROWS / 64; ++it) {
        long long row = base + (long long)it * 64 + rsub;
        if (row < nrows) {
            long long f = row * 4 + q;
            float4 a = w4[f];
            float4 b = x4[f];
            double p = (double)a.x * (double)b.x
                     + (double)a.y * (double)b.y
                     + (double)a.z * (double)b.z
                     + (double)a.w * (double)b.w;
            p += __shfl_xor(p, 1, 64);
            p += __shfl_xor(p, 2, 64);
            if (q == 0) R[row] = (float)p;
        }
    }
}

// Hillis-Steele inclusive scan over 256 affine transforms (m, sA, sB).
__device__ __forceinline__ void block_scan(double& m, double& sA, double& sB,
                                           double* mS, double* aS, double* bS) {
    int tid = threadIdx.x;
    mS[tid] = m; aS[tid] = sA; bS[tid] = sB;
    __syncthreads();
#pragma unroll
    for (int off = 1; off < BLOCK; off <<= 1) {
        double pm = 1.0, pa = 0.0, pb = 0.0;
        if (tid >= off) { pm = mS[tid - off]; pa = aS[tid - off]; pb = bS[tid - off]; }
        __syncthreads();
        if (tid >= off) {
            sA = m * pa + sA;
            sB = m * pb + sB;
            m  = pm * m;
        }
        mS[tid] = m; aS[tid] = sA; bS[tid] = sB;
        __syncthreads();
    }
}

// load this thread's LPT=8 R values (fast float4 path when fully in-range)
__device__ __forceinline__ int load_seg(const float* __restrict__ Rws,
                                        const float* __restrict__ w,
                                        const float* __restrict__ x,
                                        long long g0, int nrows, float* rv) {
    long long rem = (long long)nrows - g0;
    int len = rem >= LPT ? LPT : (rem > 0 ? (int)rem : 0);
    if (Rws) {
        if (len == LPT) {
            const float4* Rp = (const float4*)(Rws + g0);
            float4 u = Rp[0], v = Rp[1];
            rv[0]=u.x; rv[1]=u.y; rv[2]=u.z; rv[3]=u.w;
            rv[4]=v.x; rv[5]=v.y; rv[6]=v.z; rv[7]=v.w;
        } else {
            for (int k = 0; k < len; ++k) rv[k] = Rws[g0 + k];
        }
    } else {
        for (int k = 0; k < len; ++k) rv[k] = row_R(w, x, g0 + k);
    }
    return len;
}

// ---------------- K2: per-chunk affine aggregates ----------------
__global__ __launch_bounds__(BLOCK) void k2_partials(
    const float* __restrict__ Rws,
    const float* __restrict__ w, const float* __restrict__ x, int nrows,
    double* __restrict__ blkM, double* __restrict__ blkA, double* __restrict__ blkB)
{
    __shared__ double mS[BLOCK], aS[BLOCK], bS[BLOCK];
    int tid = threadIdx.x;
    long long g0 = (long long)blockIdx.x * CHUNK + (long long)tid * LPT;
    float rv[LPT];
    int len = load_seg(Rws, w, x, g0, nrows, rv);

    double m = 1.0, sA = 0.0, sB = 0.0;
    for (int k = 0; k < len; ++k) {
        double r = (double)rv[k];
        sA = D_C * sA + D_ETA * r;
        sB = D_C * sB + D_ETA * (r * r);
        m *= D_C;
    }
    block_scan(m, sA, sB, mS, aS, bS);
    if (tid == BLOCK - 1) {
        blkM[blockIdx.x] = m;
        blkA[blockIdx.x] = sA;
        blkB[blockIdx.x] = sB;
    }
}

// ---------------- K3: scan of chunk aggregates (1 block) ----------------
__global__ __launch_bounds__(BLOCK) void k3_scan(
    int nb,
    const double* __restrict__ blkM, const double* __restrict__ blkA,
    const double* __restrict__ blkB,
    double* __restrict__ A0, double* __restrict__ B0)
{
    __shared__ double mS[BLOCK], aS[BLOCK], bS[BLOCK];
    int tid = threadIdx.x;
    int K = (nb + BLOCK - 1) / BLOCK;
    int g0 = tid * K;
    int g1 = g0 + K; if (g1 > nb) g1 = nb;

    double m = 1.0, sA = 0.0, sB = 0.0;
    for (int g = g0; g < g1; ++g) {
        double mg = blkM[g], ag = blkA[g], bg = blkB[g];
        sA = mg * sA + ag;
        sB = mg * sB + bg;
        m *= mg;
    }
    block_scan(m, sA, sB, mS, aS, bS);

    double em = 1.0, ea = 0.0, eb = 0.0;
    if (tid > 0) { em = mS[tid - 1]; ea = aS[tid - 1]; eb = bS[tid - 1]; }
    double A = ea;                 // em*0 + ea
    double B = em * D_EPS + eb;
    for (int g = g0; g < g1; ++g) {
        A0[g] = A; B0[g] = B;
        double mg = blkM[g], ag = blkA[g], bg = blkB[g];
        A = mg * A + ag;
        B = mg * B + bg;
    }
}

// ---------------- K4: replay + D sum ----------------
__global__ __launch_bounds__(BLOCK) void k4_dsum(
    const float* __restrict__ Rws,
    const float* __restrict__ w, const float* __restrict__ x, int nrows,
    const double* __restrict__ A0, const double* __restrict__ B0,
    double* __restrict__ bsum)
{
    __shared__ double mS[BLOCK], aS[BLOCK], bS[BLOCK];
    __shared__ double wsum[BLOCK / 64];
    int tid = threadIdx.x;
    long long g0 = (long long)blockIdx.x * CHUNK + (long long)tid * LPT;
    float rv[LPT];
    int len = load_seg(Rws, w, x, g0, nrows, rv);

    double m = 1.0, sA = 0.0, sB = 0.0;
    for (int k = 0; k < len; ++k) {
        double r = (double)rv[k];
        sA = D_C * sA + D_ETA * r;
        sB = D_C * sB + D_ETA * (r * r);
        m *= D_C;
    }
    block_scan(m, sA, sB, mS, aS, bS);

    double em = 1.0, ea = 0.0, eb = 0.0;
    if (tid > 0) { em = mS[tid - 1]; ea = aS[tid - 1]; eb = bS[tid - 1]; }
    double A = em * A0[blockIdx.x] + ea;
    double B = em * B0[blockIdx.x] + eb;

    double dsum = 0.0;
    for (int k = 0; k < len; ++k) {
        double r = (double)rv[k];
        double dA = D_ETA * (r - A);
        double dB = D_ETA * (r * r - B);
        double var = B - A * A;
        if (var < D_EPS) var = D_EPS;
        double denom = var * sqrt(var);
        dsum += (B * dA - 0.5 * A * dB) / denom;
        A += dA;
        B += dB;
    }

#pragma unroll
    for (int off = 32; off > 0; off >>= 1) dsum += __shfl_down(dsum, off, 64);
    if ((tid & 63) == 0) wsum[tid >> 6] = dsum;
    __syncthreads();
    if (tid == 0) bsum[blockIdx.x] = wsum[0] + wsum[1] + wsum[2] + wsum[3];
}

// ---------------- K5: final reduction ----------------
__global__ __launch_bounds__(BLOCK) void k5_final(
    const double* __restrict__ bsum, int nb, int nrows, float* __restrict__ out)
{
    __shared__ double sh[BLOCK / 64];
    int tid = threadIdx.x;
    double s = 0.0;
    for (int i = tid; i < nb; i += BLOCK) s += bsum[i];
#pragma unroll
    for (int off = 32; off > 0; off >>= 1) s += __shfl_down(s, off, 64);
    if ((tid & 63) == 0) sh[tid >> 6] = s;
    __syncthreads();
    if (tid == 0) out[0] = (float)(-(sh[0] + sh[1] + sh[2] + sh[3]) / (double)nrows);
}

extern "C" void kernel_launch(void* const* d_in, const int* in_sizes, int n_in,
                              void* d_out, int out_size, void* d_ws, size_t ws_size,
                              hipStream_t stream)
{
    const float* w = (const float*)d_in[0];
    const float* x = (const float*)d_in[1];
    int nrows = in_sizes[0] / 16;
    int nb  = (nrows + CHUNK - 1) / CHUNK;
    int nb1 = (nrows + K1_ROWS - 1) / K1_ROWS;

    char* ws = (char*)d_ws;
    double* blkM = (double*)(ws + 64);
    double* blkA = blkM + nb;
    double* blkB = blkA + nb;
    double* A0   = blkB + nb;
    double* B0   = A0 + nb;
    double* bsum = B0 + nb;
    size_t off = 64 + (size_t)6 * nb * sizeof(double);
    off = (off + 255) & ~(size_t)255;
    float* Rws = nullptr;
    if (ws_size >= off + (size_t)nrows * sizeof(float))
        Rws = (float*)(ws + off);

    if (Rws)
        k1_dots<<<nb1, BLOCK, 0, stream>>>(w, x, nrows, Rws);
    k2_partials<<<nb, BLOCK, 0, stream>>>(Rws, w, x, nrows, blkM, blkA, blkB);
    k3_scan<<<1, BLOCK, 0, stream>>>(nb, blkM, blkA, blkB, A0, B0);
    k4_dsum<<<nb, BLOCK, 0, stream>>>(Rws, w, x, nrows, A0, B0, bsum);
    k5_final<<<1, BLOCK, 0, stream>>>(bsum, nb, nrows, (float*)d_out);
}